// Round 4
// baseline (908.427 us; speedup 1.0000x reference)
//
#include <hip/hip_runtime.h>
#include <stdint.h>

// Problem constants
#define Bsz 1024
#define Tn  20
#define Hn  768
#define G4n 3072   // 4*H

// Workspace layout (float offsets). Harness re-poisons ws every iteration
// (720 MiB fill, ~110us, visible in rocprof) — k_conv re-zeroes all token
// regions since poison may not be zero.
// All cross-block payloads are token-packed u64 {token<<32 | f32 bits},
// relaxed device-scope atomics, self-validating (consumer spins per datum).
#define WS_PART  0        // 256  u64: per-worker-block step partials (tok=t-1)
#define WS_BCAST 512      // 1    u64: hx broadcast (tok=t)
#define WS_STG   1024     // 19*256 u64: per-stager-wave Sev partials (tok=t)
#define WS_SHP   16384    // 256  u64: per-worker-block GEMM h0 partials (tok=1)
#define WS_RSU   32768    // 19*3072 u64: rowsum values (tok=t)
#define WS_CB    262144   // 1024*768 u64: c0 values (tok=1)
// bf16 planes (ushort), MFMA fragment order:
// chunk(rb,kb)=64 lanes x 8 elems; elem(l,e)=plane[rb*16+(l&15)][kb*32+(l>>4)*8+e]
#define WS_EVH   2097152  // ev[:,0,:]  hi   [64 rb][24 kb][512]
#define WS_EVL   2490368  // ev[:,0,:]  lo
#define WS_WH    2883584  // whh[0] {i,g,o} hi [144 rb][24 kb][512]
#define WS_WL    3768320  // whh[0] {i,g,o} lo      (end 4,653,056 floats)

// k_conv blocks: planes + token-region zeroing
#define NBC_EV   512
#define NBC_W    1152
#define NBC_Z    1672     // 22 ([0,22528)) + 114 (RSU) + 1536 (CB), 1024 f each
#define NBC_TOT  (NBC_EV + NBC_W + NBC_Z)

// k_main grid: 256 workers + 64 stagers + 1 hub (all co-resident: 321 blocks
// x 12 waves, <=2 blocks/CU with VGPR capped by launch_bounds)
#define NB_WORK  256
#define NB_STGB  64
#define HUB_BLK  (NB_WORK + NB_STGB)

typedef float  floatx4 __attribute__((ext_vector_type(4)));
typedef short  bfrag8  __attribute__((ext_vector_type(8)));

__device__ __forceinline__ float wave_reduce(float v){
#pragma unroll
    for (int o = 32; o > 0; o >>= 1) v += __shfl_down(v, o, 64);
    return v;
}
__device__ __forceinline__ float sigf(float x){ return 1.0f/(1.0f+__expf(-x)); }
__device__ __forceinline__ float tanhfast(float x){ return 2.0f/(1.0f+__expf(-2.0f*x)) - 1.0f; }
__device__ __forceinline__ unsigned short f2bf(float f){
    uint32_t u = __float_as_uint(f);
    return (unsigned short)((u + 0x7fffu + ((u>>16)&1u)) >> 16);
}
__device__ __forceinline__ float bf2f(unsigned short h){ return __uint_as_float(((uint32_t)h)<<16); }
__device__ __forceinline__ uint64_t pack_tv(unsigned t, float v){
    return ((uint64_t)t << 32) | (uint64_t)__float_as_uint(v);
}
__device__ __forceinline__ uint64_t ld_tok(const uint64_t* p){
    return __hip_atomic_load(p, __ATOMIC_RELAXED, __HIP_MEMORY_SCOPE_AGENT);
}
__device__ __forceinline__ void st_tok(uint64_t* p, uint64_t v){
    __hip_atomic_store(p, v, __ATOMIC_RELAXED, __HIP_MEMORY_SCOPE_AGENT);
}
__device__ __forceinline__ float spin_val(const uint64_t* p, unsigned want){
    uint64_t u = ld_tok(p);
    while ((unsigned)(u >> 32) != want) u = ld_tok(p);
    return __uint_as_float((uint32_t)u);
}

// ---------------- K0: bf16 hi/lo fragment-order planes + token-region zero ----------------
__global__ __launch_bounds__(256) void k_conv(
    const float* __restrict__ ev, const float* __restrict__ whh,
    float* __restrict__ ws)
{
    int bid = blockIdx.x, tid = threadIdx.x;
    if (bid < NBC_EV + NBC_W) {
        if (tid >= 192) return;
        int r = tid / 96;                 // which of the 2 rows this block covers
        int i = (tid - r*96) * 8;         // element offset 0..760
        const float* src;
        unsigned short *dh, *dl;
        int prow;
        if (bid < NBC_EV) {
            prow = bid*2 + r;             // ev row (t=0 slice)
            src = ev + (size_t)prow*(Tn*Hn) + i;
            dh = (unsigned short*)(ws + WS_EVH);
            dl = (unsigned short*)(ws + WS_EVL);
        } else {
            int p = (bid - NBC_EV)*2 + r;           // plane row 0..2303
            int gsel = p / Hn;                      // 0,1,2
            int ga = (gsel==0) ? 0 : (gsel==1 ? 2 : 3);  // gates i,g,o
            int j = ga*Hn + (p - gsel*Hn);
            prow = p;
            src = whh + (size_t)j*Hn + i;
            dh = (unsigned short*)(ws + WS_WH);
            dl = (unsigned short*)(ws + WS_WL);
        }
        int rb = prow >> 4, col = prow & 15;
        int kb = i >> 5, q = (i >> 3) & 3;
        size_t base = (((size_t)(rb*24 + kb))*64 + q*16 + col) * 8;

        float4 v0 = *(const float4*)src;
        float4 v1 = *(const float4*)(src+4);
        float f[8] = {v0.x,v0.y,v0.z,v0.w,v1.x,v1.y,v1.z,v1.w};
        bfrag8 hv, lv;
#pragma unroll
        for (int qq = 0; qq < 8; ++qq) {
            unsigned short hb = f2bf(f[qq]);
            hv[qq] = (short)hb;
            lv[qq] = (short)f2bf(f[qq] - bf2f(hb));
        }
        *(bfrag8*)(dh + base) = hv;
        *(bfrag8*)(dl + base) = lv;
    } else {
        int zb = bid - NBC_EV - NBC_W;
        size_t base;
        if      (zb <  22) base = (size_t)zb*1024;                    // [0,22528)
        else if (zb < 136) base = (size_t)WS_RSU + (size_t)(zb-22)*1024;
        else               base = (size_t)WS_CB  + (size_t)(zb-136)*1024;
        float4 z = {0.f,0.f,0.f,0.f};
        *(float4*)(ws + base + (size_t)tid*4) = z;
    }
}

// ---------------- K1: fused GEMM + staging + recurrence ----------------
// blocks 0..255   : workers  — 3 GEMM tiles (3 groups x 4 waves), then t-loop
// blocks 256..319 : stagers  — 4 waves each; wave sv computes 12 rowsum rows
//                   + 4 ev-row sums per t, racing ahead of the recurrence
// block  320      : hub      — 1 wave; aggregates shp/stg/parts, broadcasts hx
__global__ __launch_bounds__(768, 6) void k_main(
    const float* __restrict__ price, const float* __restrict__ ev,
    const float* __restrict__ wih,   const float* __restrict__ whh,
    const float* __restrict__ bih,   const float* __restrict__ bhh,
    const float* __restrict__ fcw,   const float* __restrict__ fcb,
    float* __restrict__ ws, float* __restrict__ out)
{
    __shared__ float red[12];
    __shared__ float redF[4][12];
    __shared__ float shx;

    uint64_t* part  = (uint64_t*)(ws + WS_PART);
    uint64_t* bcast = (uint64_t*)(ws + WS_BCAST);
    uint64_t* stg   = (uint64_t*)(ws + WS_STG);
    uint64_t* shp   = (uint64_t*)(ws + WS_SHP);
    uint64_t* rsu   = (uint64_t*)(ws + WS_RSU);
    uint64_t* cb    = (uint64_t*)(ws + WS_CB);

    int blk = blockIdx.x, tid = threadIdx.x;
    int lane = tid & 63, wid = tid >> 6;

    if (blk == HUB_BLK) {
        // ---------------- hub (1 wave) ----------------
        if (tid >= 64) return;
        // Sh0: 256 per-block GEMM partials, 4 slots/lane
        uint64_t u0,u1,u2,u3;
        for (;;) {
            u0 = ld_tok(&shp[lane*4+0]); u1 = ld_tok(&shp[lane*4+1]);
            u2 = ld_tok(&shp[lane*4+2]); u3 = ld_tok(&shp[lane*4+3]);
            if ((unsigned)(u0>>32)==1u && (unsigned)(u1>>32)==1u &&
                (unsigned)(u2>>32)==1u && (unsigned)(u3>>32)==1u) break;
        }
        float sh0 = wave_reduce(__uint_as_float((uint32_t)u0) + __uint_as_float((uint32_t)u1)
                              + __uint_as_float((uint32_t)u2) + __uint_as_float((uint32_t)u3));
        for (int t = 1; t < Tn; ++t) {
            // Sev[t] from 256 stager-wave partials
            const uint64_t* sg = &stg[(size_t)(t-1)*256];
            for (;;) {
                u0 = ld_tok(&sg[lane*4+0]); u1 = ld_tok(&sg[lane*4+1]);
                u2 = ld_tok(&sg[lane*4+2]); u3 = ld_tok(&sg[lane*4+3]);
                if ((unsigned)(u0>>32)==(unsigned)t && (unsigned)(u1>>32)==(unsigned)t &&
                    (unsigned)(u2>>32)==(unsigned)t && (unsigned)(u3>>32)==(unsigned)t) break;
            }
            float sev = wave_reduce(__uint_as_float((uint32_t)u0) + __uint_as_float((uint32_t)u1)
                                  + __uint_as_float((uint32_t)u2) + __uint_as_float((uint32_t)u3));
            float hsum;
            if (t == 1) {
                hsum = sh0;
            } else {
                unsigned want = (unsigned)(t-1);
                for (;;) {
                    u0 = ld_tok(&part[lane*4+0]); u1 = ld_tok(&part[lane*4+1]);
                    u2 = ld_tok(&part[lane*4+2]); u3 = ld_tok(&part[lane*4+3]);
                    if ((unsigned)(u0>>32)==want && (unsigned)(u1>>32)==want &&
                        (unsigned)(u2>>32)==want && (unsigned)(u3>>32)==want) break;
                }
                hsum = wave_reduce(__uint_as_float((uint32_t)u0) + __uint_as_float((uint32_t)u1)
                                 + __uint_as_float((uint32_t)u2) + __uint_as_float((uint32_t)u3));
            }
            if (lane == 0) st_tok(bcast, pack_tv((unsigned)t, sev + hsum));
        }
        return;
    }

    if (blk >= NB_WORK) {
        // ---------------- stager (4 waves/block, no __syncthreads) ----------------
        if (tid >= 256) return;
        int sv = (blk - NB_WORK)*4 + wid;      // 0..255
        for (int t = 1; t < Tn; ++t) {
            const float* wt = whh + (size_t)t*G4n*Hn;
            // 12 rowsum rows
            float rs[12];
#pragma unroll
            for (int r = 0; r < 12; ++r) {
                const float* base = wt + (size_t)(sv*12 + r)*Hn + (size_t)lane*4;
                float4 v0 = *(const float4*)(base);
                float4 v1 = *(const float4*)(base + 256);
                float4 v2 = *(const float4*)(base + 512);
                rs[r] = (v0.x+v0.y+v0.z+v0.w) + (v1.x+v1.y+v1.z+v1.w) + (v2.x+v2.y+v2.z+v2.w);
            }
#pragma unroll
            for (int r = 0; r < 12; ++r) {
                float v = wave_reduce(rs[r]);
                if (lane == 0)
                    st_tok(&rsu[(size_t)(t-1)*G4n + sv*12 + r], pack_tv((unsigned)t, v));
            }
            // 4 ev-row sums -> one Sev partial
            float s = 0.f;
#pragma unroll
            for (int r = 0; r < 4; ++r) {
                const float* base = ev + ((size_t)(sv*4 + r)*Tn + t)*Hn + (size_t)lane*4;
                float4 v0 = *(const float4*)(base);
                float4 v1 = *(const float4*)(base + 256);
                float4 v2 = *(const float4*)(base + 512);
                s += (v0.x+v0.y+v0.z+v0.w) + (v1.x+v1.y+v1.z+v1.w) + (v2.x+v2.y+v2.z+v2.w);
            }
            s = wave_reduce(s);
            if (lane == 0)
                st_tok(&stg[(size_t)(t-1)*256 + sv], pack_tv((unsigned)t, s));
        }
        return;
    }

    // ---------------- worker ----------------
    int k = tid;

    // ----- phase 1: GEMM, 3 tiles (group g = wid>>2, intra-group wave wg) -----
    {
        int g  = wid >> 2, wg = wid & 3;
        int tau = 3*blk + g;
        int bt = tau / 48, kt = tau % 48;
        int b0 = bt*64;
        int q = lane >> 4, col = lane & 15;

        const unsigned short* evh = (const unsigned short*)(ws + WS_EVH);
        const unsigned short* evl = (const unsigned short*)(ws + WS_EVL);
        const unsigned short* wh  = (const unsigned short*)(ws + WS_WH);
        const unsigned short* wl  = (const unsigned short*)(ws + WS_WL);

        int rb_a = bt*4 + wg;
        const unsigned short* pah = evh + (size_t)rb_a*24*512 + (size_t)lane*8;
        const unsigned short* pal = evl + (size_t)rb_a*24*512 + (size_t)lane*8;
        const unsigned short* pb0h = wh + (size_t)(  0 + kt)*24*512 + (size_t)lane*8;
        const unsigned short* pb0l = wl + (size_t)(  0 + kt)*24*512 + (size_t)lane*8;
        const unsigned short* pb1h = wh + (size_t)( 48 + kt)*24*512 + (size_t)lane*8;
        const unsigned short* pb1l = wl + (size_t)( 48 + kt)*24*512 + (size_t)lane*8;
        const unsigned short* pb2h = wh + (size_t)( 96 + kt)*24*512 + (size_t)lane*8;
        const unsigned short* pb2l = wl + (size_t)( 96 + kt)*24*512 + (size_t)lane*8;

        floatx4 acc0 = (floatx4){0.f,0.f,0.f,0.f};
        floatx4 acc1 = (floatx4){0.f,0.f,0.f,0.f};
        floatx4 acc2 = (floatx4){0.f,0.f,0.f,0.f};

#pragma unroll 4
        for (int kb = 0; kb < 24; ++kb) {
            int off = kb*512;
            bfrag8 ah  = *(const bfrag8*)(pah  + off);
            bfrag8 al  = *(const bfrag8*)(pal  + off);
            bfrag8 b0h = *(const bfrag8*)(pb0h + off);
            bfrag8 b0l = *(const bfrag8*)(pb0l + off);
            acc0 = __builtin_amdgcn_mfma_f32_16x16x32_bf16(ah, b0h, acc0, 0,0,0);
            acc0 = __builtin_amdgcn_mfma_f32_16x16x32_bf16(ah, b0l, acc0, 0,0,0);
            acc0 = __builtin_amdgcn_mfma_f32_16x16x32_bf16(al, b0h, acc0, 0,0,0);
            bfrag8 b1h = *(const bfrag8*)(pb1h + off);
            bfrag8 b1l = *(const bfrag8*)(pb1l + off);
            acc1 = __builtin_amdgcn_mfma_f32_16x16x32_bf16(ah, b1h, acc1, 0,0,0);
            acc1 = __builtin_amdgcn_mfma_f32_16x16x32_bf16(ah, b1l, acc1, 0,0,0);
            acc1 = __builtin_amdgcn_mfma_f32_16x16x32_bf16(al, b1h, acc1, 0,0,0);
            bfrag8 b2h = *(const bfrag8*)(pb2h + off);
            bfrag8 b2l = *(const bfrag8*)(pb2l + off);
            acc2 = __builtin_amdgcn_mfma_f32_16x16x32_bf16(ah, b2h, acc2, 0,0,0);
            acc2 = __builtin_amdgcn_mfma_f32_16x16x32_bf16(ah, b2l, acc2, 0,0,0);
            acc2 = __builtin_amdgcn_mfma_f32_16x16x32_bf16(al, b2h, acc2, 0,0,0);
        }

        int k0 = kt*16;
        int j0 = 0*Hn + k0 + col;
        int j1 = 2*Hn + k0 + col;
        int j2 = 3*Hn + k0 + col;
        float4 w0 = *(const float4*)(wih + (size_t)j0*4);
        float4 w1 = *(const float4*)(wih + (size_t)j1*4);
        float4 w2 = *(const float4*)(wih + (size_t)j2*4);
        float bb0 = bih[j0] + bhh[j0];
        float bb1 = bih[j1] + bhh[j1];
        float bb2 = bih[j2] + bhh[j2];

        float hsum = 0.f;
#pragma unroll
        for (int r = 0; r < 4; ++r) {
            int b = b0 + wg*16 + q*4 + r;
            float4 xv = *(const float4*)(price + (size_t)b*(Tn*4));
            float gi = acc0[r] + xv.x*w0.x + xv.y*w0.y + xv.z*w0.z + xv.w*w0.w + bb0;
            float gg = acc1[r] + xv.x*w1.x + xv.y*w1.y + xv.z*w1.z + xv.w*w1.w + bb1;
            float go = acc2[r] + xv.x*w2.x + xv.y*w2.y + xv.z*w2.z + xv.w*w2.w + bb2;
            float c0 = sigf(gi) * tanhfast(gg);
            float h0 = sigf(go) * tanhfast(c0);
            st_tok(&cb[(size_t)b*Hn + k0 + col], pack_tv(1u, c0));
            hsum += h0;
        }
        hsum = wave_reduce(hsum);
        if (lane == 0) red[wid] = hsum;
        __syncthreads();
        if (tid == 0) {
            float tot = 0.f;
#pragma unroll
            for (int i = 0; i < 12; ++i) tot += red[i];
            st_tok(&shp[blk], pack_tv(1u, tot));
        }
    }

    // ----- phase 2: recurrence t=1..19 -----
    float c[4];
    float fcwk = fcw[k];
    float fcb0 = fcb[0];
    float hsum_prev = 0.f;
    float vout[4] = {0.f,0.f,0.f,0.f};

    for (int t = 1; t < Tn; ++t) {
        // publish previous step's block partial (token t-1)
        if (t >= 2) {
            float v = wave_reduce(hsum_prev);
            if (lane == 0) red[wid] = v;
            __syncthreads();
            if (tid == 0) {
                float tot = 0.f;
#pragma unroll
                for (int i = 0; i < 12; ++i) tot += red[i];
                st_tok(&part[blk], pack_tv((unsigned)(t-1), tot));
            }
        }

        // preload step-t coefficients (rowsum via self-validating tokens)
        const float* wih_t = wih + (size_t)t*G4n*4;
        float4 pvv[4];
#pragma unroll
        for (int e = 0; e < 4; ++e)
            pvv[e] = *(const float4*)(price + (size_t)(blk + 256*e)*(Tn*4) + t*4);

        float rsv[4], base[4][4];
#pragma unroll
        for (int g = 0; g < 4; ++g) {
            int j = g*Hn + k;
            float4 wv = *(const float4*)(wih_t + (size_t)j*4);
            rsv[g] = spin_val(&rsu[(size_t)(t-1)*G4n + j], (unsigned)t);
            float bs = bih[(size_t)t*G4n + j] + bhh[(size_t)t*G4n + j];
#pragma unroll
            for (int e = 0; e < 4; ++e) {
                base[e][g] = pvv[e].x*wv.x + pvv[e].y*wv.y
                           + pvv[e].z*wv.z + pvv[e].w*wv.w + bs;
            }
        }

        // c0 handoff (self-validating, produced by other blocks' GEMM)
        if (t == 1) {
#pragma unroll
            for (int e = 0; e < 4; ++e)
                c[e] = spin_val(&cb[(size_t)(blk + 256*e)*Hn + k], 1u);
        }

        // obtain hx_t from hub broadcast
        if (tid == 0) {
            uint64_t u;
            do { u = ld_tok(bcast); }
            while ((unsigned)(u >> 32) < (unsigned)t);
            shx = __uint_as_float((uint32_t)u);
        }
        __syncthreads();
        float hx = shx;

        // cell update
        float hsum = 0.f;
#pragma unroll
        for (int e = 0; e < 4; ++e) {
            float gi = base[e][0] + hx*rsv[0];
            float gf = base[e][1] + hx*rsv[1];
            float gg = base[e][2] + hx*rsv[2];
            float go = base[e][3] + hx*rsv[3];
            float cn = sigf(gf)*c[e] + sigf(gi)*tanhfast(gg);
            c[e] = cn;
            float h = sigf(go)*tanhfast(cn);
            hsum += h;
            if (t == Tn-1) vout[e] = wave_reduce(h * fcwk);
        }
        hsum_prev = hsum;
    }

    // epilogue: out[b] = h19[b,:].fc_w + fc_b
    if (lane == 0) {
#pragma unroll
        for (int e = 0; e < 4; ++e) redF[e][wid] = vout[e];
    }
    __syncthreads();
    if (tid < 4) {
        float tot = 0.f;
#pragma unroll
        for (int i = 0; i < 12; ++i) tot += redF[tid][i];
        out[blk + 256*tid] = tot + fcb0;
    }
}

extern "C" void kernel_launch(void* const* d_in, const int* in_sizes, int n_in,
                              void* d_out, int out_size, void* d_ws, size_t ws_size,
                              hipStream_t stream)
{
    const float* price = (const float*)d_in[0];
    const float* ev    = (const float*)d_in[1];
    const float* wih   = (const float*)d_in[2];
    const float* whh   = (const float*)d_in[3];
    const float* bih   = (const float*)d_in[4];
    const float* bhh   = (const float*)d_in[5];
    const float* fcw   = (const float*)d_in[6];
    const float* fcb   = (const float*)d_in[7];
    float* out = (float*)d_out;
    float* ws  = (float*)d_ws;

    k_conv<<<NBC_TOT, 256, 0, stream>>>(ev, whh, ws);
    k_main<<<HUB_BLK + 1, 768, 0, stream>>>(price, ev, wih, whh, bih, bhh,
                                            fcw, fcb, ws, out);
}